// Round 7
// baseline (135.909 us; speedup 1.0000x reference)
//
#include <hip/hip_runtime.h>
#include <math.h>

typedef float f32x4 __attribute__((ext_vector_type(4)));

// Problem constants
#define B_     16
#define C_     32
#define D_     2
#define HW_    4096               // 64*64
#define NPIX   (B_ * D_ * HW_)    // 131072 pixels
#define NPAIRP 576                // padded pair slots: row c has rlen(c)=4*(c/4+1)
#define NROWSP 592                // + zero rows (margin in d_ws)

// ---------------------------------------------------------------------------
// Prep (validated R2-R5): fold weight [O,C,C] into padded symmetric pair table
//   wpad[kp][o]. Row c starts at kpbase(c)=4*(c+2a(a-1)+ab), a=c>>2, b=c&3.
//   Slot j<=c: W[o,c,j]+W[o,j,c] (diag once); pad slots = 0.
// ---------------------------------------------------------------------------
__global__ void prep_wsym(const float* __restrict__ w, float* __restrict__ wpad) {
    int idx = blockIdx.x * blockDim.x + threadIdx.x;
    const int total1 = 32 * 32 * 32;
    const int totalz = (NROWSP - NPAIRP) * 32;
    if (idx < total1) {
        int o = idx & 31;
        int j = (idx >> 5) & 31;
        int c = idx >> 10;
        int a = c >> 2, b = c & 3;
        int rlen = (a + 1) << 2;
        if (j >= rlen) return;
        int kb = 4 * (c + 2 * a * (a - 1) + a * b);
        float v = 0.0f;
        if (j <= c) {
            const float* wo = w + o * (C_ * C_);
            v = (j == c) ? wo[c * C_ + c] : (wo[c * C_ + j] + wo[j * C_ + c]);
        }
        wpad[(kb + j) * 32 + o] = v;
    } else if (idx < total1 + totalz) {
        wpad[NPAIRP * 32 + (idx - total1)] = 0.0f;
    }
}

// ---------------------------------------------------------------------------
// Main kernel. Block = 256 threads = 4 waves over the SAME 128 pixels:
//   wave (wv, pg): wv = o-half (16 outputs), pg = pixel group (64 px).
//
// All inner-loop memory is LDS (pure in-order DS on lgkmcnt -> compiler emits
// counted waits, pipelines; R5 proved this sustains >=74% issue):
//   - trig[c][cos|sin][128]: computed once in prologue (32 sincos/pixel),
//     read lane-stride-1 (2 lanes/bank, conflict-free; R3-R5 measured 0).
//   - weights: staged in 4 row-aligned chunks (slot ranges 0/144/288/420/576,
//     each ends on a pair-row boundary), <=19,968 B. Inner reads are
//     wave-uniform ds_read_b128 = bank broadcast (cheap per R5's evidence).
// LDS total 52,736 B -> 3 blocks/CU = 12 waves/CU = 3 waves/SIMD.
// No SMEM and no VMEM in the compute loop -> no lgkmcnt(0) drains (R3/R4's
// 66% cap), no L1 broadcast storms (R2), no sincos bloat (R5).
// ---------------------------------------------------------------------------
#define TPB   256
#define MAXCH 156   // max chunk slots (phase 3: rows 27..31 = 156 slots)

__global__ __launch_bounds__(TPB, 3) void bilinear_kernel(
    const float* __restrict__ x,
    const float* __restrict__ wpad,
    const float* __restrict__ bias,
    float* __restrict__ out)
{
    __shared__ float trig[C_][2][128];   // 32,768 B
    __shared__ f32x4 wch[MAXCH * 8];     // 19,968 B

    const int l   = threadIdx.x & 63;
    const int wv  = (threadIdx.x >> 6) & 1;   // o-half
    const int pg  = threadIdx.x >> 7;         // pixel group
    const int pix = (pg << 6) + l;
    const int P0  = blockIdx.x * 128;
    const int b   = P0 >> 13;
    const int d   = (P0 >> 12) & 1;
    const int hw0 = P0 & 4095;                // 128-aligned, stays in (b,d)
    const int base = b * (C_ * D_ * HW_) + d * HW_ + hw0;

    // ---- prologue: 256 threads stage 128 pixels x 32 channels of cos/sin ----
    {
        const int sp  = threadIdx.x & 127;    // staging pixel
        const int chh = threadIdx.x >> 7;     // channel half
        #pragma unroll 4
        for (int cc = 0; cc < 16; ++cc) {
            int c = chh * 16 + cc;
            float xv = x[base + sp + c * (D_ * HW_)];
            float s, co;
            __sincosf(xv, &s, &co);
            trig[c][0][sp] = co;
            trig[c][1][sp] = s;
        }
    }

    float accr[16], acci[16];
    #pragma unroll
    for (int q = 0; q < 16; ++q) { accr[q] = 0.f; acci[q] = 0.f; }

    // Phase tables: chunk slot boundaries (row-aligned) and row ranges.
    const int ph_kb[5] = {0, 144, 288, 420, 576};
    const int ph_c0[5] = {0, 15, 22, 27, 32};

    #pragma unroll 1
    for (int ph = 0; ph < 4; ++ph) {
        const int kb0 = ph_kb[ph];
        __syncthreads();   // prior chunk fully consumed (ph=0: trig written)
        {   // stage this chunk: (slots)*8 f32x4 from global (L2/L3-hot)
            const f32x4* __restrict__ src = (const f32x4*)wpad + kb0 * 8;
            const int n4 = (ph_kb[ph + 1] - kb0) * 8;
            for (int i = threadIdx.x; i < n4; i += TPB) wch[i] = src[i];
        }
        __syncthreads();

        int krow = kb0;
        const int c_end = ph_c0[ph + 1];
        #pragma unroll 1
        for (int c = ph_c0[ph]; c < c_end; ++c) {
            const float cv = trig[c][0][pix];
            const float sv = trig[c][1][pix];
            const int ng   = (c >> 2) + 1;
            const int kloc = krow - kb0;
            #pragma unroll 1
            for (int g = 0; g < ng; ++g) {
                const int e0 = g << 2;
                float ce[4], se[4];
                #pragma unroll
                for (int j = 0; j < 4; ++j) {
                    ce[j] = trig[e0 + j][0][pix];
                    se[j] = trig[e0 + j][1][pix];
                }
                // wave-uniform: 16 ds_read_b128 broadcasts per group
                const f32x4* __restrict__ wr = wch + (kloc + e0) * 8 + (wv << 2);
                #pragma unroll
                for (int p = 0; p < 4; ++p) {
                    const float ur = fmaf(cv, ce[p], -(sv * se[p]));
                    const float ui = fmaf(cv, se[p],   sv * ce[p]);
                    const f32x4 w0 = wr[p * 8 + 0];
                    const f32x4 w1 = wr[p * 8 + 1];
                    const f32x4 w2 = wr[p * 8 + 2];
                    const f32x4 w3 = wr[p * 8 + 3];
                    #pragma unroll
                    for (int j = 0; j < 4; ++j) {
                        accr[j]      = fmaf(w0[j], ur, accr[j]);
                        acci[j]      = fmaf(w0[j], ui, acci[j]);
                        accr[4 + j]  = fmaf(w1[j], ur, accr[4 + j]);
                        acci[4 + j]  = fmaf(w1[j], ui, acci[4 + j]);
                        accr[8 + j]  = fmaf(w2[j], ur, accr[8 + j]);
                        acci[8 + j]  = fmaf(w2[j], ui, acci[8 + j]);
                        accr[12 + j] = fmaf(w3[j], ur, accr[12 + j]);
                        acci[12 + j] = fmaf(w3[j], ui, acci[12 + j]);
                    }
                }
            }
            krow += ((c >> 2) + 1) << 2;   // += rowlen(c)
        }
    }

    // ---- epilogue: angle + bias, coalesced stores ----
    #pragma unroll
    for (int q = 0; q < 16; ++q) {
        const int o = wv * 16 + q;
        out[base + pix + o * (D_ * HW_)] = atan2f(acci[q], accr[q]) + bias[o];
    }
}

// ---------------------------------------------------------------------------
extern "C" void kernel_launch(void* const* d_in, const int* in_sizes, int n_in,
                              void* d_out, int out_size, void* d_ws, size_t ws_size,
                              hipStream_t stream) {
    const float* x    = (const float*)d_in[0];
    const float* w    = (const float*)d_in[1];
    const float* bias = (const float*)d_in[2];
    float* out        = (float*)d_out;
    float* wpad       = (float*)d_ws;   // needs NROWSP*32*4 = 75,776 B

    {
        int n = 32 * 32 * 32 + (NROWSP - NPAIRP) * 32;
        int tpb = 256;
        prep_wsym<<<(n + tpb - 1) / tpb, tpb, 0, stream>>>(w, wpad);
    }
    {
        int grid = NPIX / 128;   // 1024 blocks, 4 waves each
        bilinear_kernel<<<grid, TPB, 0, stream>>>(x, wpad, bias, out);
    }
}

// Round 9
// 55.333 us; speedup vs baseline: 2.4562x; 2.4562x over previous
//
#include <hip/hip_runtime.h>
#include <math.h>

typedef float    f32x4 __attribute__((ext_vector_type(4)));
typedef _Float16 f16x8 __attribute__((ext_vector_type(8)));

// Problem constants
#define HW_    4096
#define CH_STR 8192          // channel (or o) stride in x/out = D*HW
#define B_STR  262144        // batch stride = C*D*HW
#define NPIX   131072
#define NKSTEP 20            // 640 padded k-slots / 32
#define NSLICE 80            // 640 / 8
#define NBEL   (2*NKSTEP*2*64*8)   // frag elems: var*kstep*ohalf*lane*j = 40960

// Scales: u' = 1024*u, w' = 512*w  ->  acc = 2^19 * oc; atan2 is scale-invariant.
// Keeps fp16 split residuals (|ul| ~ 2^-12*|u'|, |wl| ~ 2^-11*|w'|) in the
// fp16 NORMAL range so HW subnormal-flush cannot bite.
#define WSCALE 512.0f
#define USCALE 1024.0f

// d_ws layout: frag _Float16[40960] at +0 (81,920 B); ce_tab u32[80] at +81920.

// ---------------------------------------------------------------------------
// Prep: k-enumeration = rows c padded to rlen8(c)=8*(c/8+1) slots (total 640).
// frag[var][ks][oh][lane][j] = fp16 RNE split (var=0 hi, var=1 residual) of
//   512 * foldW at k = ks*32 + 8*(lane>>4) + j,  o = oh*16 + (lane&15)
//   fold: e<c -> W[o,c,e]+W[o,e,c]; e==c -> W[o,c,c]; e>c (pad) -> 0.
// ce_tab[s] = (c<<16)|e0 for 8-k slice s (each slice lies in one row c).
// ---------------------------------------------------------------------------
__global__ void prep(const float* __restrict__ w,
                     _Float16* __restrict__ bfr,
                     unsigned int* __restrict__ ct) {
    int idx = blockIdx.x * 256 + threadIdx.x;
    if (idx < NBEL) {
        int j    =  idx & 7;
        int lane = (idx >> 3) & 63;
        int oh   = (idx >> 9) & 1;
        int t    =  idx >> 10;
        int ks   = t % NKSTEP;
        int var  = t / NKSTEP;
        int k = ks * 32 + ((lane >> 4) << 3) + j;
        int c = 0, base = 0;
        for (; c < 32; ++c) { int rl = 8 * ((c >> 3) + 1); if (k < base + rl) break; base += rl; }
        int e = k - base;
        int o = oh * 16 + (lane & 15);
        float v = 0.0f;
        if (e <= c)
            v = (e == c) ? w[o * 1024 + c * 33]
                         : (w[o * 1024 + c * 32 + e] + w[o * 1024 + e * 32 + c]);
        v *= WSCALE;
        _Float16 h = (_Float16)v;                    // RNE hi
        if (var) h = (_Float16)(v - (float)h);       // RNE residual (lo)
        bfr[idx] = h;
    } else if (idx < NBEL + NSLICE) {
        int s = idx - NBEL, k = s * 8, c = 0, base = 0;
        for (; c < 32; ++c) { int rl = 8 * ((c >> 3) + 1); if (k < base + rl) break; base += rl; }
        ct[s] = ((unsigned int)c << 16) | (unsigned int)(k - base);
    }
}

// ---------------------------------------------------------------------------
// Main: block = 256 thr = 4 waves, each wave owns 16 px (block = 64 px).
// Wave tile 16px x 32o via 2 C-fragments; K = 640 in 20 steps of 32.
// Lane l: A-row px = 16*wv + (l&15); k-slice = 8*(l>>4)+j (HW A layout; any
// HW k-permutation cancels since B uses the same (lane,j)->k map).
// u = 1024*z_c*z_e built in registers from LDS fp32 trig, fp16-RNE-split;
// acc = Ah*Bh + Ah*Bl + Al*Bh in fp32 MFMA accumulators (err ~2^-23 rel).
// No barriers (each wave touches only its own 16 trig rows). B prefetched.
// ---------------------------------------------------------------------------
#define TPB 256

__global__ __launch_bounds__(TPB, 4) void mfma_bilinear(
    const float* __restrict__ x,
    const _Float16* __restrict__ bfr,
    const unsigned int* __restrict__ ct,
    const float* __restrict__ bias,
    float* __restrict__ out)
{
    __shared__ float trig[64 * 68];   // [px][0..31]=cos, [36..67]=sin (17,408 B)

    const int lane = threadIdx.x & 63;
    const int wv   = threadIdx.x >> 6;       // wave id 0..3
    const int lg   = lane >> 4;              // k-subgroup 0..3
    const int lidm = lane & 15;              // A-row / B-col within fragment
    const int P0   = blockIdx.x * 64;
    const int b    = P0 >> 13;
    const int d    = (P0 >> 12) & 1;
    const int hw0  = P0 & 4095;              // 64-aligned, block stays in (b,d)
    const int obase = b * B_STR + d * HW_ + hw0;   // + px + (c|o)*CH_STR

    const int px = wv * 16 + lidm;           // block-local pixel (my A-row)
    float* tp = trig + px * 68;

    // ---- trig prologue: my px, channels c = lg*8 + m (4 lanes cover 32 c) ----
    #pragma unroll
    for (int m = 0; m < 8; ++m) {
        int c = lg * 8 + m;
        float xv = x[obase + px + c * CH_STR];
        float s, co; __sincosf(xv, &s, &co);
        tp[c]      = co;
        tp[36 + c] = s;
    }
    // no __syncthreads needed: trig rows are wave-private (same-wave lockstep).

    f32x4 acc_r[2] = {{0.f,0.f,0.f,0.f}, {0.f,0.f,0.f,0.f}};
    f32x4 acc_i[2] = {{0.f,0.f,0.f,0.f}, {0.f,0.f,0.f,0.f}};

    const f16x8* __restrict__ bfv = (const f16x8*)bfr;  // 16B units
    f16x8 bh0 = bfv[(( 0 + 0) * 2 + 0) * 64 + lane];
    f16x8 bh1 = bfv[(( 0 + 0) * 2 + 1) * 64 + lane];
    f16x8 bl0 = bfv[((NKSTEP + 0) * 2 + 0) * 64 + lane];
    f16x8 bl1 = bfv[((NKSTEP + 0) * 2 + 1) * 64 + lane];
    unsigned int stab = ct[lg];

    #pragma unroll 1
    for (int ks = 0; ks < NKSTEP; ++ks) {
        const int kn = (ks < NKSTEP - 1) ? ks + 1 : ks;
        f16x8 nbh0 = bfv[(( 0 + kn) * 2 + 0) * 64 + lane];
        f16x8 nbh1 = bfv[(( 0 + kn) * 2 + 1) * 64 + lane];
        f16x8 nbl0 = bfv[((NKSTEP + kn) * 2 + 0) * 64 + lane];
        f16x8 nbl1 = bfv[((NKSTEP + kn) * 2 + 1) * 64 + lane];
        unsigned int nst = ct[kn * 4 + lg];

        const int c  = stab >> 16;
        const int e0 = stab & 0xffff;        // multiple of 8
        const float cc = tp[c]      * USCALE;
        const float sc = tp[36 + c] * USCALE;
        const f32x4 ce0 = *(const f32x4*)(tp + e0);
        const f32x4 ce1 = *(const f32x4*)(tp + e0 + 4);
        const f32x4 se0 = *(const f32x4*)(tp + 36 + e0);
        const f32x4 se1 = *(const f32x4*)(tp + 40 + e0);

        f16x8 ahr, ahi, alr, ali;
        #pragma unroll
        for (int j = 0; j < 8; ++j) {
            const float cej = (j < 4) ? ce0[j] : ce1[j - 4];
            const float sej = (j < 4) ? se0[j] : se1[j - 4];
            const float ur = fmaf(cc, cej, -(sc * sej));   // 1024 * Re(z_c z_e)
            const float ui = fmaf(cc, sej,   sc * cej);    // 1024 * Im(z_c z_e)
            const _Float16 urh = (_Float16)ur;             // RNE
            const _Float16 uih = (_Float16)ui;
            ahr[j] = urh;
            ahi[j] = uih;
            alr[j] = (_Float16)(ur - (float)urh);          // RNE residual
            ali[j] = (_Float16)(ui - (float)uih);
        }

        acc_r[0] = __builtin_amdgcn_mfma_f32_16x16x32_f16(ahr, bh0, acc_r[0], 0, 0, 0);
        acc_i[0] = __builtin_amdgcn_mfma_f32_16x16x32_f16(ahi, bh0, acc_i[0], 0, 0, 0);
        acc_r[1] = __builtin_amdgcn_mfma_f32_16x16x32_f16(ahr, bh1, acc_r[1], 0, 0, 0);
        acc_i[1] = __builtin_amdgcn_mfma_f32_16x16x32_f16(ahi, bh1, acc_i[1], 0, 0, 0);
        acc_r[0] = __builtin_amdgcn_mfma_f32_16x16x32_f16(ahr, bl0, acc_r[0], 0, 0, 0);
        acc_i[0] = __builtin_amdgcn_mfma_f32_16x16x32_f16(ahi, bl0, acc_i[0], 0, 0, 0);
        acc_r[1] = __builtin_amdgcn_mfma_f32_16x16x32_f16(ahr, bl1, acc_r[1], 0, 0, 0);
        acc_i[1] = __builtin_amdgcn_mfma_f32_16x16x32_f16(ahi, bl1, acc_i[1], 0, 0, 0);
        acc_r[0] = __builtin_amdgcn_mfma_f32_16x16x32_f16(alr, bh0, acc_r[0], 0, 0, 0);
        acc_i[0] = __builtin_amdgcn_mfma_f32_16x16x32_f16(ali, bh0, acc_i[0], 0, 0, 0);
        acc_r[1] = __builtin_amdgcn_mfma_f32_16x16x32_f16(alr, bh1, acc_r[1], 0, 0, 0);
        acc_i[1] = __builtin_amdgcn_mfma_f32_16x16x32_f16(ali, bh1, acc_i[1], 0, 0, 0);

        bh0 = nbh0; bh1 = nbh1; bl0 = nbl0; bl1 = nbl1; stab = nst;
    }

    // ---- epilogue: C/D (m89): col o = oh*16 + (lane&15), row px = 4*lg + q ----
    #pragma unroll
    for (int oh = 0; oh < 2; ++oh) {
        const int o = oh * 16 + lidm;
        const float bo = bias[o];
        #pragma unroll
        for (int q = 0; q < 4; ++q) {
            const int pxr = wv * 16 + lg * 4 + q;
            out[obase + pxr + o * CH_STR] = atan2f(acc_i[oh][q], acc_r[oh][q]) + bo;
        }
    }
}

// ---------------------------------------------------------------------------
extern "C" void kernel_launch(void* const* d_in, const int* in_sizes, int n_in,
                              void* d_out, int out_size, void* d_ws, size_t ws_size,
                              hipStream_t stream) {
    const float* x    = (const float*)d_in[0];
    const float* w    = (const float*)d_in[1];
    const float* bias = (const float*)d_in[2];
    float* out        = (float*)d_out;
    _Float16*     bfr = (_Float16*)d_ws;                          // 81,920 B
    unsigned int* ct  = (unsigned int*)((char*)d_ws + 81920);     // 320 B

    {
        int n = NBEL + NSLICE;
        prep<<<(n + 255) / 256, 256, 0, stream>>>(w, bfr, ct);
    }
    {
        int grid = NPIX / 64;   // 2048 blocks x 4 waves
        mfma_bilinear<<<grid, TPB, 0, stream>>>(x, bfr, ct, bias, out);
    }
}

// Round 11
// 53.350 us; speedup vs baseline: 2.5475x; 1.0372x over previous
//
#include <hip/hip_runtime.h>
#include <math.h>

typedef float    f32x4 __attribute__((ext_vector_type(4)));
typedef _Float16 f16x2 __attribute__((ext_vector_type(2)));
typedef _Float16 f16x4 __attribute__((ext_vector_type(4)));
typedef _Float16 f16x8 __attribute__((ext_vector_type(8)));
typedef __fp16   h16x2 __attribute__((ext_vector_type(2)));   // cvt_pkrtz return type

// Problem constants
#define HW_    4096
#define CH_STR 8192          // channel (or o) stride in x/out = D*HW
#define B_STR  262144        // batch stride = C*D*HW
#define NPIX   131072
#define NKSTEP 20            // 640 padded k-slots / 32
#define NSLICE 80            // 640 / 8
#define NBEL   (2*NKSTEP*2*64*8)   // frag elems: var*kstep*ohalf*lane*j = 40960

// Scales: u' = 1024*u, w' = 512*w  ->  acc = 2^19 * oc; atan2 is scale-invariant.
// Keeps fp16 split residuals in the fp16 NORMAL range (no subnormal flush).
#define WSCALE 512.0f
#define USCALE 1024.0f

// d_ws layout: frag _Float16[40960] at +0 (81,920 B); ce_tab u32[80] at +81920.

// ---------------------------------------------------------------------------
// Prep (validated R8): k-enumeration = rows c padded to rlen8(c)=8*(c/8+1)
// slots (total 640). frag[var][ks][oh][lane][j] = fp16 RNE split (var=0 hi,
// var=1 residual) of 512*foldW at k = ks*32 + 8*(lane>>4) + j,
// o = oh*16 + (lane&15); fold: e<c -> W[o,c,e]+W[o,e,c]; e==c -> W[o,c,c];
// pad -> 0. ce_tab[s] = (c<<16)|e0 per 8-k slice s.
// ---------------------------------------------------------------------------
__global__ void prep(const float* __restrict__ w,
                     _Float16* __restrict__ bfr,
                     unsigned int* __restrict__ ct) {
    int idx = blockIdx.x * 256 + threadIdx.x;
    if (idx < NBEL) {
        int j    =  idx & 7;
        int lane = (idx >> 3) & 63;
        int oh   = (idx >> 9) & 1;
        int t    =  idx >> 10;
        int ks   = t % NKSTEP;
        int var  = t / NKSTEP;
        int k = ks * 32 + ((lane >> 4) << 3) + j;
        int c = 0, base = 0;
        for (; c < 32; ++c) { int rl = 8 * ((c >> 3) + 1); if (k < base + rl) break; base += rl; }
        int e = k - base;
        int o = oh * 16 + (lane & 15);
        float v = 0.0f;
        if (e <= c)
            v = (e == c) ? w[o * 1024 + c * 33]
                         : (w[o * 1024 + c * 32 + e] + w[o * 1024 + e * 32 + c]);
        v *= WSCALE;
        _Float16 h = (_Float16)v;                    // RNE hi
        if (var) h = (_Float16)(v - (float)h);       // RNE residual (lo)
        bfr[idx] = h;
    } else if (idx < NBEL + NSLICE) {
        int s = idx - NBEL, k = s * 8, c = 0, base = 0;
        for (; c < 32; ++c) { int rl = 8 * ((c >> 3) + 1); if (k < base + rl) break; base += rl; }
        ct[s] = ((unsigned int)c << 16) | (unsigned int)(k - base);
    }
}

// ---------------------------------------------------------------------------
// Main (structure validated R8; R10 = R9 + pkrtz bit_cast compile fix).
// Block = 256 thr = 4 waves, each wave owns 16 px. Wave tile 16px x 32o,
// K = 640 in 20 steps of 32. A built in registers (HW A layout; any HW
// k-permutation cancels: B uses the same (lane,j)->k map).
// acc = Ah*Bh + Ah*Bl + Al*Bh in fp32 MFMA accumulators.
// Pipeline: B frags, slice word, AND trig vectors all prefetched one full
// k-step ahead -> every load has ~1 iteration of latency slack.
// ---------------------------------------------------------------------------
#define TPB 256

__device__ __forceinline__ f16x8 mk8(f16x2 a, f16x2 b, f16x2 c, f16x2 d) {
    f16x4 ab = __builtin_shufflevector(a, b, 0, 1, 2, 3);
    f16x4 cd = __builtin_shufflevector(c, d, 0, 1, 2, 3);
    return __builtin_shufflevector(ab, cd, 0, 1, 2, 3, 4, 5, 6, 7);
}

__device__ __forceinline__ f16x2 pkrtz(float a, float b) {
    return __builtin_bit_cast(f16x2, __builtin_amdgcn_cvt_pkrtz(a, b));
}

#define LOAD_TRIG(ST, CC, SC, CE0, CE1, SE0, SE1) do { \
    const int c_ = (int)((ST) >> 16), e_ = (int)((ST) & 0xffffu); \
    CC  = tp[c_]; \
    SC  = tp[36 + c_]; \
    CE0 = *(const f32x4*)(tp + e_); \
    CE1 = *(const f32x4*)(tp + e_ + 4); \
    SE0 = *(const f32x4*)(tp + 36 + e_); \
    SE1 = *(const f32x4*)(tp + 40 + e_); \
} while (0)

__global__ __launch_bounds__(TPB, 4) void mfma_bilinear(
    const float* __restrict__ x,
    const _Float16* __restrict__ bfr,
    const unsigned int* __restrict__ ct,
    const float* __restrict__ bias,
    float* __restrict__ out)
{
    __shared__ float trig[64 * 68];   // [px][0..31]=cos, [36..67]=sin (17,408 B)

    const int lane = threadIdx.x & 63;
    const int wv   = threadIdx.x >> 6;       // wave id 0..3
    const int lg   = lane >> 4;              // k-subgroup 0..3
    const int lidm = lane & 15;              // A-row / B-col within fragment
    const int P0   = blockIdx.x * 64;
    const int b    = P0 >> 13;
    const int d    = (P0 >> 12) & 1;
    const int hw0  = P0 & 4095;              // 64-aligned, block stays in (b,d)
    const int obase = b * B_STR + d * HW_ + hw0;   // + px + (c|o)*CH_STR

    const int px = wv * 16 + lidm;           // block-local pixel (my A-row)
    float* tp = trig + px * 68;

    // ---- trig prologue: 4 lanes (lg=0..3) cover the 32 channels of px ----
    #pragma unroll
    for (int m = 0; m < 8; ++m) {
        int c = lg * 8 + m;
        float xv = x[obase + px + c * CH_STR];
        float s, co; __sincosf(xv, &s, &co);
        tp[c]      = co;
        tp[36 + c] = s;
    }
    // same-wave DS ordering makes the reads below safe without a barrier.

    f32x4 acc_r[2] = {{0.f,0.f,0.f,0.f}, {0.f,0.f,0.f,0.f}};
    f32x4 acc_i[2] = {{0.f,0.f,0.f,0.f}, {0.f,0.f,0.f,0.f}};

    const f16x8* __restrict__ bfv = (const f16x8*)bfr;  // 16B units

    // ---- pipeline prologue: state for ks=0 + slice word for ks=1 ----
    f16x8 bh0 = bfv[((0) * 2 + 0) * 64 + lane];
    f16x8 bh1 = bfv[((0) * 2 + 1) * 64 + lane];
    f16x8 bl0 = bfv[((NKSTEP) * 2 + 0) * 64 + lane];
    f16x8 bl1 = bfv[((NKSTEP) * 2 + 1) * 64 + lane];
    unsigned int st0 = ct[lg];
    float cc, sc; f32x4 ce0, ce1, se0, se1;
    LOAD_TRIG(st0, cc, sc, ce0, ce1, se0, se1);
    unsigned int stN = ct[4 + lg];           // slice word for ks=1

    #pragma unroll 2
    for (int ks = 0; ks < NKSTEP; ++ks) {
        const int kn  = (ks < NKSTEP - 1) ? ks + 1 : ks;
        const int knn = (kn < NKSTEP - 1) ? kn + 1 : kn;

        // ---- issue ALL next-iteration loads first (one k-step of slack) ----
        f16x8 nbh0 = bfv[(( 0 + kn) * 2 + 0) * 64 + lane];
        f16x8 nbh1 = bfv[(( 0 + kn) * 2 + 1) * 64 + lane];
        f16x8 nbl0 = bfv[((NKSTEP + kn) * 2 + 0) * 64 + lane];
        f16x8 nbl1 = bfv[((NKSTEP + kn) * 2 + 1) * 64 + lane];
        float ncc, nsc; f32x4 nce0, nce1, nse0, nse1;
        LOAD_TRIG(stN, ncc, nsc, nce0, nce1, nse0, nse1);
        unsigned int stNN = ct[knn * 4 + lg];

        // ---- compute current k-step ----
        const float ccs = cc * USCALE;
        const float scs = sc * USCALE;

        f16x2 hr[4], hi[4], lr[4], li[4];
        #pragma unroll
        for (int p = 0; p < 4; ++p) {
            const float cea = (2*p     < 4) ? ce0[2*p]     : ce1[2*p - 4];
            const float sea = (2*p     < 4) ? se0[2*p]     : se1[2*p - 4];
            const float ceb = (2*p + 1 < 4) ? ce0[2*p + 1] : ce1[2*p - 3];
            const float seb = (2*p + 1 < 4) ? se0[2*p + 1] : se1[2*p - 3];
            const float ur0 = fmaf(ccs, cea, -(scs * sea));
            const float ui0 = fmaf(ccs, sea,   scs * cea);
            const float ur1 = fmaf(ccs, ceb, -(scs * seb));
            const float ui1 = fmaf(ccs, seb,   scs * ceb);
            hr[p] = pkrtz(ur0, ur1);                       // packed hi (RTZ)
            hi[p] = pkrtz(ui0, ui1);
            lr[p] = pkrtz(ur0 - (float)hr[p][0],
                          ur1 - (float)hr[p][1]);          // exact residual
            li[p] = pkrtz(ui0 - (float)hi[p][0],
                          ui1 - (float)hi[p][1]);
        }
        const f16x8 ahr = mk8(hr[0], hr[1], hr[2], hr[3]);
        const f16x8 ahi = mk8(hi[0], hi[1], hi[2], hi[3]);
        const f16x8 alr = mk8(lr[0], lr[1], lr[2], lr[3]);
        const f16x8 ali = mk8(li[0], li[1], li[2], li[3]);

        acc_r[0] = __builtin_amdgcn_mfma_f32_16x16x32_f16(ahr, bh0, acc_r[0], 0, 0, 0);
        acc_i[0] = __builtin_amdgcn_mfma_f32_16x16x32_f16(ahi, bh0, acc_i[0], 0, 0, 0);
        acc_r[1] = __builtin_amdgcn_mfma_f32_16x16x32_f16(ahr, bh1, acc_r[1], 0, 0, 0);
        acc_i[1] = __builtin_amdgcn_mfma_f32_16x16x32_f16(ahi, bh1, acc_i[1], 0, 0, 0);
        acc_r[0] = __builtin_amdgcn_mfma_f32_16x16x32_f16(ahr, bl0, acc_r[0], 0, 0, 0);
        acc_i[0] = __builtin_amdgcn_mfma_f32_16x16x32_f16(ahi, bl0, acc_i[0], 0, 0, 0);
        acc_r[1] = __builtin_amdgcn_mfma_f32_16x16x32_f16(ahr, bl1, acc_r[1], 0, 0, 0);
        acc_i[1] = __builtin_amdgcn_mfma_f32_16x16x32_f16(ahi, bl1, acc_i[1], 0, 0, 0);
        acc_r[0] = __builtin_amdgcn_mfma_f32_16x16x32_f16(alr, bh0, acc_r[0], 0, 0, 0);
        acc_i[0] = __builtin_amdgcn_mfma_f32_16x16x32_f16(ali, bh0, acc_i[0], 0, 0, 0);
        acc_r[1] = __builtin_amdgcn_mfma_f32_16x16x32_f16(alr, bh1, acc_r[1], 0, 0, 0);
        acc_i[1] = __builtin_amdgcn_mfma_f32_16x16x32_f16(ali, bh1, acc_i[1], 0, 0, 0);

        // ---- rotate pipeline state ----
        bh0 = nbh0; bh1 = nbh1; bl0 = nbl0; bl1 = nbl1;
        cc = ncc; sc = nsc;
        ce0 = nce0; ce1 = nce1; se0 = nse0; se1 = nse1;
        stN = stNN;
    }

    // ---- epilogue: C/D (m89): col o = oh*16 + (lane&15), row px = 4*lg + q ----
    #pragma unroll
    for (int oh = 0; oh < 2; ++oh) {
        const int o = oh * 16 + lidm;
        const float bo = bias[o];
        #pragma unroll
        for (int q = 0; q < 4; ++q) {
            const int pxr = wv * 16 + lg * 4 + q;
            out[obase + pxr + o * CH_STR] = atan2f(acc_i[oh][q], acc_r[oh][q]) + bo;
        }
    }
}

// ---------------------------------------------------------------------------
extern "C" void kernel_launch(void* const* d_in, const int* in_sizes, int n_in,
                              void* d_out, int out_size, void* d_ws, size_t ws_size,
                              hipStream_t stream) {
    const float* x    = (const float*)d_in[0];
    const float* w    = (const float*)d_in[1];
    const float* bias = (const float*)d_in[2];
    float* out        = (float*)d_out;
    _Float16*     bfr = (_Float16*)d_ws;                          // 81,920 B
    unsigned int* ct  = (unsigned int*)((char*)d_ws + 81920);     // 320 B

    {
        int n = NBEL + NSLICE;
        prep<<<(n + 255) / 256, 256, 0, stream>>>(w, bfr, ct);
    }
    {
        int grid = NPIX / 64;   // 2048 blocks x 4 waves
        mfma_bilinear<<<grid, TPB, 0, stream>>>(x, bfr, ct, bias, out);
    }
}